// Round 10
// baseline (503.421 us; speedup 1.0000x reference)
//
#include <hip/hip_runtime.h>
#include <stdint.h>

#define DIM 1024
#define GLOBAL_AS __attribute__((address_space(1)))
#define LDS_AS __attribute__((address_space(3)))

typedef short bf16x8 __attribute__((ext_vector_type(8)));
typedef float f32x4 __attribute__((ext_vector_type(4)));

// deg-4 Taylor via depth-2: R = I + A + A2/2 + (C3*A + C4*A2)*A2
#define C3f 0.16666667f
#define C4f 0.041666668f

__device__ __forceinline__ unsigned short f32_to_bf16(float f) {
    union { float f; uint32_t u; } v; v.f = f;
    uint32_t u = v.u;
    u += 0x7FFFu + ((u >> 16) & 1u);   // round-to-nearest-even
    return (unsigned short)(u >> 16);
}
__device__ __forceinline__ float bf16_to_f32(unsigned short u) {
    union { uint32_t u; float f; } v; v.u = ((uint32_t)u) << 16;
    return v.f;
}

// async global->LDS, 16B per lane; LDS dst = wave-uniform base + lane*16.
__device__ __forceinline__ void async16(const void* g, void* l) {
    __builtin_amdgcn_global_load_lds((GLOBAL_AS const void*)g,
                                     (LDS_AS void*)l, 16, 0, 0);
}

// Manual device barrier (monotonic counter, zeroed per launch by memset).
// Proven correct in R8 (passed, absmax 0.03125). Deadlock-free here because
// launch_bounds(256,4) caps VGPR at 128 -> 4 blocks/CU guaranteed; LDS
// 4 x 32 KB = 128 <= 160 KB -> all 1024 blocks co-resident.
__device__ __forceinline__ void gbar(unsigned* ctr, unsigned target) {
    __syncthreads();
    if (threadIdx.x == 0) {
        __threadfence();
        __hip_atomic_fetch_add(ctr, 1u, __ATOMIC_ACQ_REL,
                               __HIP_MEMORY_SCOPE_AGENT);
        while (__hip_atomic_load(ctr, __ATOMIC_ACQUIRE,
                                 __HIP_MEMORY_SCOPE_AGENT) < target)
            __builtin_amdgcn_s_sleep(8);
        __threadfence();
    }
    __syncthreads();
}

// ---- R10: the whole R-chain + X conversion in ONE launch ----
// Model from R0-R9: per-launch fixed cost ~15-20 us dominates the chain
// (5 structurally different chains all ~108-124 us). R8's fusion measured
// 119 us but ran at 2 blocks/CU with 256 serial convert blocks; this version
// fixes the structure: 1024 blocks at 4/CU, every block converts 96 KB of X
// in S0 and computes one 32x32 tile in S1/S2 (R9's verified GEMM bodies).
//   S0: A = W - W^T (1 tile/block) + all X fp32->bf16 (grid-stride)
//   S1: A2 = A*A; epilogue A2b = bf16(A2), Pb = bf16(C3*A + C4*A2)
//   S2: T = P*A2; epilogue R = T + I + A + A2/2 -> R^T bf16 (Rtb)
__global__ __launch_bounds__(256, 4) void k_fused(
        const float* __restrict__ W, const float* __restrict__ X,
        unsigned short* __restrict__ Ab, unsigned short* __restrict__ G,
        unsigned short* __restrict__ A2b, unsigned short* __restrict__ Pb,
        unsigned short* __restrict__ Rtb, unsigned short* __restrict__ Xb,
        unsigned* __restrict__ bar) {
    __shared__ unsigned short lA[32 * 256];   // 16 KB
    __shared__ unsigned short lB[32 * 256];   // 16 KB
    int bid = blockIdx.x, tid = threadIdx.x;
    int lane = tid & 63, w = tid >> 6;
    int wr = w >> 1, wc = w & 1;              // 2x2 wave grid, 16x16 each
    int rr = lane & 15, ko = lane >> 4;

    // ---- S0a: A = W - W^T via 32x32 LDS transpose (1 tile/block) ----
    {
        float (*t2)[33] = (float(*)[33])lA;   // 4.2 KB alias
        int i0 = (bid & 31) * 32, j0 = (bid >> 5) * 32;
        int tx = tid & 31, ty = tid >> 5;
        float t1[4];
        #pragma unroll
        for (int p = 0; p < 4; p++) {
            int r = p * 8 + ty;
            t1[p] = W[(i0 + r) * DIM + j0 + tx];        // coalesced
            t2[r][tx] = W[(j0 + r) * DIM + i0 + tx];    // coalesced
        }
        __syncthreads();
        #pragma unroll
        for (int p = 0; p < 4; p++) {
            int r = p * 8 + ty;
            float a = t1[p] - t2[tx][r];                // W[i][j]-W[j][i]
            int gi = (i0 + r) * DIM + j0 + tx;
            Ab[gi] = f32_to_bf16(a);
            G[gi]  = f32_to_bf16(-a);
        }
    }
    // ---- S0b: convert all X fp32 -> Xb bf16 (8 chunks/thread) ----
    #pragma unroll
    for (int it = 0; it < 8; it++) {
        size_t id = (size_t)it * 262144 + (size_t)bid * 256 + tid;
        const f32x4* p = (const f32x4*)(X + id * 8);
        f32x4 v0 = p[0], v1 = p[1];
        unsigned short o[8];
        #pragma unroll
        for (int q = 0; q < 4; q++) { o[q] = f32_to_bf16(v0[q]); o[4 + q] = f32_to_bf16(v1[q]); }
        *(bf16x8*)&Xb[id * 8] = *(bf16x8*)o;
    }
    gbar(bar, 1024);

    int m0 = (bid & 31) * 32, n0 = (bid >> 5) * 32;

    // ---- S1: A2 = A * A (G rows = A^T = B-operand); epilogue A2b, Pb ----
    {
        f32x4 acc = {};
        for (int ks = 0; ks < 4; ks++) {
            int kb = ks * 256;
            #pragma unroll
            for (int i = 0; i < 4; i++) {
                int l = i * 256 + tid;        // 0..1023 = 32 rows x 32 chunks
                int r = l >> 5, cst = l & 31;
                int cd = cst ^ (r & 7);
                async16(&Ab[(m0 + r) * DIM + kb + cd * 8], &lA[l * 8]);
                async16(&G[(n0 + r) * DIM + kb + cd * 8], &lB[l * 8]);
            }
            __syncthreads();
            #pragma unroll
            for (int s = 0; s < 8; s++) {
                int cd = s * 4 + ko;
                int ra = wr * 16 + rr;
                int rb = wc * 16 + rr;
                bf16x8 af = *(const bf16x8*)&lA[ra * 256 + ((cd ^ (ra & 7)) * 8)];
                bf16x8 bq = *(const bf16x8*)&lB[rb * 256 + ((cd ^ (rb & 7)) * 8)];
                acc = __builtin_amdgcn_mfma_f32_16x16x32_bf16(af, bq, acc, 0, 0, 0);
            }
            __syncthreads();
        }
        #pragma unroll
        for (int q = 0; q < 4; q++) {
            int rl = wr * 16 + ko * 4 + q;
            int cl = wc * 16 + rr;
            int gi = (m0 + rl) * DIM + n0 + cl;
            float v = acc[q];
            A2b[gi] = f32_to_bf16(v);
            float a = bf16_to_f32(Ab[gi]);
            Pb[gi] = f32_to_bf16(C3f * a + C4f * v);
        }
    }
    gbar(bar, 2048);

    // ---- S2: T = P * A2 (A2 symmetric -> Qt = A2b); epilogue R^T ----
    {
        f32x4 acc = {};
        for (int ks = 0; ks < 4; ks++) {
            int kb = ks * 256;
            #pragma unroll
            for (int i = 0; i < 4; i++) {
                int l = i * 256 + tid;
                int r = l >> 5, cst = l & 31;
                int cd = cst ^ (r & 7);
                async16(&Pb[(m0 + r) * DIM + kb + cd * 8], &lA[l * 8]);
                async16(&A2b[(n0 + r) * DIM + kb + cd * 8], &lB[l * 8]);
            }
            __syncthreads();
            #pragma unroll
            for (int s = 0; s < 8; s++) {
                int cd = s * 4 + ko;
                int ra = wr * 16 + rr;
                int rb = wc * 16 + rr;
                bf16x8 af = *(const bf16x8*)&lA[ra * 256 + ((cd ^ (ra & 7)) * 8)];
                bf16x8 bq = *(const bf16x8*)&lB[rb * 256 + ((cd ^ (rb & 7)) * 8)];
                acc = __builtin_amdgcn_mfma_f32_16x16x32_bf16(af, bq, acc, 0, 0, 0);
            }
            __syncthreads();
        }
        // R = acc + I + A + A2/2; LDS-transpose; Rtb = bf16(R^T)
        float* tb = (float*)lA;               // 32*33*4 = 4.2 KB
        #pragma unroll
        for (int q = 0; q < 4; q++) {
            int rl = wr * 16 + ko * 4 + q;
            int cl = wc * 16 + rr;
            int gi = (m0 + rl) * DIM + n0 + cl;
            float a = bf16_to_f32(Ab[gi]);
            float a2 = bf16_to_f32(A2b[gi]);
            float d = (m0 + rl == n0 + cl) ? 1.0f : 0.0f;
            tb[cl * 33 + rl] = acc[q] + d + a + 0.5f * a2;
        }
        __syncthreads();
        #pragma unroll
        for (int q = 0; q < 4; q++) {
            int l = tid * 4 + q;              // 1024 elements
            int orow = l >> 5, ocol = l & 31;
            Rtb[(n0 + orow) * DIM + m0 + ocol] = f32_to_bf16(tb[orow * 33 + ocol]);
        }
    }
}

// Out(16384x1024) = Xb(bf16) @ R, R^T row-major bf16 (Rtb).
// Measured champion (41-43 us, MfmaUtil ~31%): 128x128 tiles, BK=64,
// 32 KB LDS, grid 1024 = 4 blocks/CU; bid%8 == m%8 keeps an m-strip's
// n-tiles on one XCD.
__global__ __launch_bounds__(256, 4) void k_biggemm(
        const unsigned short* __restrict__ Xb,
        const unsigned short* __restrict__ Rtb,
        float* __restrict__ Out) {
    __shared__ unsigned short lX[128 * 64];   // 16 KB
    __shared__ unsigned short lB[128 * 64];   // 16 KB
    int tid = threadIdx.x;
    int bid = blockIdx.x;
    int m0 = (bid & 127) * 128, n0 = (bid >> 7) * 128;
    int lane = tid & 63, w = tid >> 6;
    int wr = w >> 1, wc = w & 1;
    int rr = lane & 15, ko = lane >> 4;
    f32x4 acc[4][4] = {};
    for (int kb = 0; kb < DIM; kb += 64) {
        #pragma unroll
        for (int i = 0; i < 4; i++) {         // 128 rows x 8 chunks each array
            int l = i * 256 + tid;
            int r = l >> 3, cst = l & 7;
            int cd = cst ^ (r & 7);
            async16(&Xb[(size_t)(m0 + r) * DIM + kb + cd * 8], &lX[l * 8]);
            async16(&Rtb[(n0 + r) * DIM + kb + cd * 8], &lB[l * 8]);
        }
        __syncthreads();
        #pragma unroll
        for (int s = 0; s < 2; s++) {
            int cd = s * 4 + ko;
            bf16x8 af[4], bq[4];
            #pragma unroll
            for (int mi = 0; mi < 4; mi++) {
                int ra = wr * 64 + mi * 16 + rr;
                af[mi] = *(const bf16x8*)&lX[ra * 64 + ((cd ^ (ra & 7)) * 8)];
            }
            #pragma unroll
            for (int ni = 0; ni < 4; ni++) {
                int rb = wc * 64 + ni * 16 + rr;
                bq[ni] = *(const bf16x8*)&lB[rb * 64 + ((cd ^ (rb & 7)) * 8)];
            }
            #pragma unroll
            for (int mi = 0; mi < 4; mi++)
                #pragma unroll
                for (int ni = 0; ni < 4; ni++)
                    acc[mi][ni] = __builtin_amdgcn_mfma_f32_16x16x32_bf16(
                        af[mi], bq[ni], acc[mi][ni], 0, 0, 0);
        }
        __syncthreads();
    }
    #pragma unroll
    for (int mi = 0; mi < 4; mi++)
        #pragma unroll
        for (int ni = 0; ni < 4; ni++)
            #pragma unroll
            for (int q = 0; q < 4; q++) {
                int row = m0 + wr * 64 + mi * 16 + ko * 4 + q;
                int col = n0 + wc * 64 + ni * 16 + rr;
                Out[(size_t)row * DIM + col] = acc[mi][ni][q];
            }
}

extern "C" void kernel_launch(void* const* d_in, const int* in_sizes, int n_in,
                              void* d_out, int out_size, void* d_ws, size_t ws_size,
                              hipStream_t stream) {
    const float* X = (const float*)d_in[0];        // 4*4096*1024 fp32
    const float* W = (const float*)d_in[1];        // 1024*1024 fp32
    float* Out = (float*)d_out;                    // 16384*1024 fp32
    char* ws = (char*)d_ws;
    const size_t MB = 1u << 20;
    unsigned short* Ab  = (unsigned short*)(ws + 0 * MB);
    unsigned short* G   = (unsigned short*)(ws + 2 * MB);
    unsigned short* A2b = (unsigned short*)(ws + 4 * MB);
    unsigned short* Pb  = (unsigned short*)(ws + 6 * MB);
    unsigned short* Rtb = (unsigned short*)(ws + 8 * MB);
    unsigned short* Xb  = (unsigned short*)(ws + 10 * MB);  // 32 MB -> ends 42
    unsigned* bar = (unsigned*)(ws + 42 * MB);              // 8 B counter

    // zero the barrier counter (stream-ordered, graph-capturable; R8-proven)
    hipMemsetAsync(bar, 0, 8, stream);
    // whole R-chain + X conversion: ONE launch, 1024 blocks, 4/CU co-resident
    k_fused<<<1024, 256, 0, stream>>>(W, X, Ab, G, A2b, Pb, Rtb, Xb, bar);
    // big GEMM: 1024 blocks (128 m x 8 n), 128x128 tiles, 4 blocks/CU.
    k_biggemm<<<1024, 256, 0, stream>>>(Xb, Rtb, Out);
}